// Round 11
// baseline (327.593 us; speedup 1.0000x reference)
//
#include <hip/hip_runtime.h>
#include <hip/hip_bf16.h>

// BERT_SCL: loss = 0.9 * supcon(cls_emb, labels) + 0.1 * CE(pooled@W.T + b, labels)
// d_out[0] = loss, d_out[1..57344] = logits (8192 x 7, f32)
//
// e8 = fp8_e4m3(row-normalized cls * 1/sqrt(TEMP)). S_ij = e8_i.e8_j <= M=1/TEMP
// -> fixed-max logsumexp. possum_i = e8_i.T_{l_i} - ||e8_i||^2 (positive mask is
// linear in S) -> the big GEMM computes ONLY exp-sums, via MX-scaled fp8 MFMA
// (16x16x128, unit scales 0x7F) = 2x bf16 rate. S symmetric -> upper-tri tiles
// (2080), off-diag emit row AND col sums. Supertile swizzle (8x8) for L2.
//
// TWO nodes. Node 2 is multi-role with device-scope counters (the r8/r9-proven
// atomicAdd + __hip_atomic_load agent readback pattern):
//   blk 0..63   classumA -> partial (agent atomic stores), hist; doneA++
//   blk 64..84  spin doneA==64; T = sum partials (atomic ld/st); doneMain++
//   blk 85..2164 gemm tile (r9 code, unchanged); doneMain++
//   last 32 doneMain finishers: spin doneMain==2101 (<=31 blocks left -> brief,
//   deadlock-free), rowfinal 256-row slice (T cached in LDS), contr; last
//   done2 finisher writes out[0].
//
// Ledger: r2 hot-address atomics; r3 supertile swizzle; r4 never force waves/EU
// (spill tripwire); r5 <1blk/CU latency-bound; r6 ~node overhead -> fuse;
// r7 non-scaled fp8 = bf16 rate; r9 scaled-MFMA gemm 63.7us proven (3.19M
// conflicts from dual-b128 frag reads ~5us, open); r10 hipLaunchCooperativeKernel
// FAILS graph capture (out never written) -> counters/spin instead, never coop.

#define B_N 8192
#define D_K 768
#define NLAB 7
#define MBOUND 3.3333333333333335f /* 1/TEMP */
#define RTINV 1.8257418583505538f  /* 1/sqrt(TEMP) */
#define NABLK 64  /* classumA blocks */
#define GOFF 85   /* gemm blocks start (64 A + 21 B) */
#define NTILE 2080
#define NWORK 2101 /* 21 B + 2080 gemm increment doneMain */
#define NTAIL 32

typedef float f32x4 __attribute__((ext_vector_type(4)));
typedef int i32x8 __attribute__((ext_vector_type(8)));

__device__ __forceinline__ void gl2lds16(const void* g, void* l) {
  __builtin_amdgcn_global_load_lds(
      (const __attribute__((address_space(1))) void*)g,
      (__attribute__((address_space(3))) void*)l, 16, 0, 0);
}

// exact fp8 e4m3fn -> f32 decode
__device__ __forceinline__ float dec8(unsigned int b) {
  unsigned int s = (b >> 7) & 1u, e = (b >> 3) & 15u, m = b & 7u;
  float fn = __uint_as_float((s << 31) | ((e + 120u) << 23) | (m << 20));
  float fs = (s ? -1.f : 1.f) * (float)m * 0.001953125f;  // m * 2^-9
  return e ? fn : fs;
}

__device__ __forceinline__ float aldf(const float* p) {
  return __hip_atomic_load(p, __ATOMIC_RELAXED, __HIP_MEMORY_SCOPE_AGENT);
}
__device__ __forceinline__ int aldi(const int* p) {
  return __hip_atomic_load(p, __ATOMIC_RELAXED, __HIP_MEMORY_SCOPE_AGENT);
}
__device__ __forceinline__ void astf(float* p, float v) {
  __hip_atomic_store(p, v, __ATOMIC_RELAXED, __HIP_MEMORY_SCOPE_AGENT);
}

// ---- node 1: zero accums + normalize->fp8 + logits + CE ----
__global__ __launch_bounds__(256) void k_prep(
    const float* __restrict__ cls, const float* __restrict__ pooled,
    const int* __restrict__ labels, const float* __restrict__ W,
    const float* __restrict__ bias, unsigned char* __restrict__ e8,
    float* __restrict__ logits_out, float* __restrict__ celoss,
    int* __restrict__ zr) {
  if (blockIdx.x == 0)
    for (int t = threadIdx.x; t < 8256; t += 256) zr[t] = 0;  // rse + counters

  int wv = threadIdx.x >> 6, lane = threadIdx.x & 63;
  int row = blockIdx.x * 4 + wv;

  const float4* src = (const float4*)(cls + (size_t)row * D_K);
  float4 x[3];
  float ss = 0.f;
#pragma unroll
  for (int j = 0; j < 3; ++j) {
    x[j] = src[j * 64 + lane];
    ss += x[j].x * x[j].x + x[j].y * x[j].y + x[j].z * x[j].z + x[j].w * x[j].w;
  }
#pragma unroll
  for (int m = 1; m < 64; m <<= 1) ss += __shfl_xor(ss, m);
  float sc = rsqrtf(ss) * RTINV;
  int* d8 = (int*)(e8 + (size_t)row * D_K);
#pragma unroll
  for (int j = 0; j < 3; ++j) {
    int w32 = __builtin_amdgcn_cvt_pk_fp8_f32(x[j].x * sc, x[j].y * sc, 0, false);
    w32 = __builtin_amdgcn_cvt_pk_fp8_f32(x[j].z * sc, x[j].w * sc, w32, true);
    d8[j * 64 + lane] = w32;
  }

  const float4* p4 = (const float4*)(pooled + (size_t)row * D_K);
  float acc[NLAB];
#pragma unroll
  for (int c = 0; c < NLAB; ++c) acc[c] = 0.f;
#pragma unroll
  for (int j = 0; j < 3; ++j) {
    float4 xx = p4[j * 64 + lane];
#pragma unroll
    for (int c = 0; c < NLAB; ++c) {
      float4 w = ((const float4*)(W + c * D_K))[j * 64 + lane];
      acc[c] += xx.x * w.x + xx.y * w.y + xx.z * w.z + xx.w * w.w;
    }
  }
#pragma unroll
  for (int c = 0; c < NLAB; ++c)
#pragma unroll
    for (int m = 1; m < 64; m <<= 1) acc[c] += __shfl_xor(acc[c], m);
  if (lane == 0) {
    float l[NLAB], mx = -1e30f;
#pragma unroll
    for (int c = 0; c < NLAB; ++c) { l[c] = acc[c] + bias[c]; mx = fmaxf(mx, l[c]); }
    float se = 0.f;
#pragma unroll
    for (int c = 0; c < NLAB; ++c) se += __expf(l[c] - mx);
    float lse = mx + __logf(se);
    celoss[row] = lse - l[labels[row]];
    float* o = logits_out + (size_t)row * NLAB;
#pragma unroll
    for (int c = 0; c < NLAB; ++c) o[c] = l[c];
  }
}

// ---- node 2: multi-role mega kernel ----
__global__ __launch_bounds__(256) void k_mega(
    const unsigned char* __restrict__ e8, const int* __restrict__ labels,
    float* __restrict__ rse, int* __restrict__ hist, int* __restrict__ doneA,
    int* __restrict__ doneMain, int* __restrict__ done2,
    float* __restrict__ contr, float* __restrict__ T,
    const float* __restrict__ celoss, float* __restrict__ partial,
    float* __restrict__ outv) {
  __shared__ __align__(16) unsigned char SM[32896];
  unsigned char* As = SM;
  unsigned char* Bs = SM + 16384;
  int* sBcast = (int*)(SM + 32768);
  int* Hl = (int*)(SM + 32800);
  float* sPart = (float*)(SM + 32832);

  const int tid = threadIdx.x, blk = blockIdx.x;
  const int wv = tid >> 6, lane = tid & 63;
  const int quad = lane >> 4, cix = lane & 15;
  int n;

  if (blk < NABLK) {
    // ===== role A: classum partials + hist (128 rows per block) =====
    int r0 = blk * 128;
    if (tid < 192) {
      float acc[NLAB][4];
#pragma unroll
      for (int c = 0; c < NLAB; ++c)
#pragma unroll
        for (int k = 0; k < 4; ++k) acc[c][k] = 0.f;
      for (int r = 0; r < 128; r += 4) {
        int lab[4];
        uchar4 u[4];
#pragma unroll
        for (int q = 0; q < 4; ++q) {
          int row = r0 + r + q;
          lab[q] = labels[row];
          u[q] = *(const uchar4*)(e8 + (size_t)row * D_K + tid * 4);
        }
#pragma unroll
        for (int q = 0; q < 4; ++q) {
          float x0 = dec8(u[q].x), x1 = dec8(u[q].y);
          float x2 = dec8(u[q].z), x3 = dec8(u[q].w);
#pragma unroll
          for (int c = 0; c < NLAB; ++c) {
            bool m = (lab[q] == c);
            acc[c][0] += m ? x0 : 0.f;
            acc[c][1] += m ? x1 : 0.f;
            acc[c][2] += m ? x2 : 0.f;
            acc[c][3] += m ? x3 : 0.f;
          }
        }
      }
      float* dst = partial + (size_t)blk * (NLAB * D_K);
#pragma unroll
      for (int c = 0; c < NLAB; ++c)
#pragma unroll
        for (int k = 0; k < 4; ++k) astf(dst + c * D_K + tid * 4 + k, acc[c][k]);
    } else {
      int ln = tid - 192;
      int cnt[NLAB];
#pragma unroll
      for (int c = 0; c < NLAB; ++c) cnt[c] = 0;
#pragma unroll
      for (int q = 0; q < 2; ++q) {
        int lab = labels[r0 + q * 64 + ln];
#pragma unroll
        for (int c = 0; c < NLAB; ++c) cnt[c] += (lab == c);
      }
#pragma unroll
      for (int c = 0; c < NLAB; ++c)
#pragma unroll
        for (int m = 1; m < 64; m <<= 1) cnt[c] += __shfl_xor(cnt[c], m);
      if (ln == 0)
#pragma unroll
        for (int c = 0; c < NLAB; ++c) atomicAdd(&hist[c], cnt[c]);
    }
    __syncthreads();  // waitcnt drain: all stores/atomics complete
    if (tid == 0) { __threadfence(); atomicAdd(doneA, 1); }
    return;
  } else if (blk < GOFF) {
    // ===== role B: T = sum of partials (after A completes) =====
    if (tid == 0) {
      while (aldi(doneA) < NABLK) {}
    }
    __syncthreads();
    __threadfence();
    int idx = (blk - NABLK) * 256 + tid;  // exactly covers 21*256 = 5376
    float v = 0.f;
    for (int g = 0; g < NABLK; ++g) v += aldf(partial + (size_t)g * (NLAB * D_K) + idx);
    astf(T + idx, v);
    __syncthreads();
    if (tid == 0) { __threadfence(); *sBcast = atomicAdd(doneMain, 1); }
    __syncthreads();
    n = *sBcast;
  } else {
    // ===== role GEMM: one upper-tri 128x128 tile (r9 code, unchanged) =====
    int rem = blk - GOFF;
    int BI = 0, BJ = 0;
    for (;;) {
      int sz = (BI == BJ) ? 36 : 64;
      if (rem < sz) break;
      rem -= sz;
      if (++BJ == 8) { ++BI; BJ = BI; }
    }
    int bi, bj;
    if (BI == BJ) {
      int r = 0, w = 8;
      while (rem >= w) { rem -= w; ++r; --w; }
      bi = BI * 8 + r;
      bj = BJ * 8 + r + rem;
    } else {
      bi = BI * 8 + (rem >> 3);
      bj = BJ * 8 + (rem & 7);
    }
    const int i0 = bi * 128, j0 = bj * 128;
    const int rowTile = 64 * (wv >> 1), colTile = 64 * (wv & 1);

    f32x4 acc[4][4] = {};
    for (int kc = 0; kc < 6; ++kc) {
      __syncthreads();
#pragma unroll
      for (int it = 0; it < 4; ++it) {
        int s = it * 256 + tid;     // 16B slot
        int r = s >> 3;             // row 0..127
        int p = ((s & 7) - r) & 7;  // inverse of rotate swizzle
        int lbase = (it * 256 + wv * 64) * 16;
        gl2lds16(e8 + (size_t)(i0 + r) * D_K + kc * 128 + p * 16, (char*)As + lbase);
        gl2lds16(e8 + (size_t)(j0 + r) * D_K + kc * 128 + p * 16, (char*)Bs + lbase);
      }
      __syncthreads();
      i32x8 aF[4];
#pragma unroll
      for (int mt = 0; mt < 4; ++mt) {
        int r = rowTile + 16 * mt + cix;
        const char* base = (const char*)As + r * 128;
        int4 lo = *(const int4*)(base + (((quad * 2 + 0) + r) & 7) * 16);
        int4 hi = *(const int4*)(base + (((quad * 2 + 1) + r) & 7) * 16);
        aF[mt][0] = lo.x; aF[mt][1] = lo.y; aF[mt][2] = lo.z; aF[mt][3] = lo.w;
        aF[mt][4] = hi.x; aF[mt][5] = hi.y; aF[mt][6] = hi.z; aF[mt][7] = hi.w;
      }
#pragma unroll
      for (int nt = 0; nt < 4; ++nt) {  // bF streamed: 1 live frag
        int r = colTile + 16 * nt + cix;
        const char* base = (const char*)Bs + r * 128;
        int4 lo = *(const int4*)(base + (((quad * 2 + 0) + r) & 7) * 16);
        int4 hi = *(const int4*)(base + (((quad * 2 + 1) + r) & 7) * 16);
        i32x8 bF;
        bF[0] = lo.x; bF[1] = lo.y; bF[2] = lo.z; bF[3] = lo.w;
        bF[4] = hi.x; bF[5] = hi.y; bF[6] = hi.z; bF[7] = hi.w;
#pragma unroll
        for (int mt = 0; mt < 4; ++mt)
          acc[mt][nt] = __builtin_amdgcn_mfma_scale_f32_16x16x128_f8f6f4(
              aF[mt], bF, acc[mt][nt], 0, 0, 0, 127, 0, 127);  // fp8, scale=1
      }
    }

    // epilogue: exp-sums (16x16 C/D: col=lane&15, row=quad*4+rg)
    if (bi != bj) {
      float ce_col[4] = {0.f, 0.f, 0.f, 0.f};
#pragma unroll
      for (int mt = 0; mt < 4; ++mt) {
        int rowbase = i0 + rowTile + 16 * mt + quad * 4;
        float rs_e[4] = {0.f, 0.f, 0.f, 0.f};
#pragma unroll
        for (int nt = 0; nt < 4; ++nt) {
#pragma unroll
          for (int rg = 0; rg < 4; ++rg) {
            float e = __expf(acc[mt][nt][rg] - MBOUND);
            rs_e[rg] += e;
            ce_col[nt] += e;
          }
        }
#pragma unroll
        for (int rg = 0; rg < 4; ++rg)
#pragma unroll
          for (int m = 1; m <= 8; m <<= 1) rs_e[rg] += __shfl_xor(rs_e[rg], m);
        if (cix == 0)
#pragma unroll
          for (int rg = 0; rg < 4; ++rg) atomicAdd(&rse[rowbase + rg], rs_e[rg]);
      }
#pragma unroll
      for (int nt = 0; nt < 4; ++nt) {
        ce_col[nt] += __shfl_xor(ce_col[nt], 16);
        ce_col[nt] += __shfl_xor(ce_col[nt], 32);
      }
      if (quad == 0)
#pragma unroll
        for (int nt = 0; nt < 4; ++nt)
          atomicAdd(&rse[j0 + colTile + 16 * nt + cix], ce_col[nt]);
    } else {
#pragma unroll
      for (int mt = 0; mt < 4; ++mt) {
        int rowbase = i0 + rowTile + 16 * mt + quad * 4;
        float rs_e[4] = {0.f, 0.f, 0.f, 0.f};
#pragma unroll
        for (int nt = 0; nt < 4; ++nt) {
          int gcol = j0 + colTile + 16 * nt + cix;
#pragma unroll
          for (int rg = 0; rg < 4; ++rg) {
            bool dg = (rowbase + rg) == gcol;
            rs_e[rg] += dg ? 0.f : __expf(acc[mt][nt][rg] - MBOUND);
          }
        }
#pragma unroll
        for (int rg = 0; rg < 4; ++rg)
#pragma unroll
          for (int m = 1; m <= 8; m <<= 1) rs_e[rg] += __shfl_xor(rs_e[rg], m);
        if (cix == 0)
#pragma unroll
          for (int rg = 0; rg < 4; ++rg) atomicAdd(&rse[rowbase + rg], rs_e[rg]);
      }
    }
    __syncthreads();  // waitcnt drain: all rse atomics complete
    if (tid == 0) { __threadfence(); *sBcast = atomicAdd(doneMain, 1); }
    __syncthreads();
    n = *sBcast;
  }

  // ===== tail: last 32 doneMain finishers do rowfinal slices =====
  if (n >= NWORK - NTAIL) {
    int slice = n - (NWORK - NTAIL);  // 0..31 -> rows [slice*256, slice*256+256)
    if (tid == 0) {
      while (aldi(doneMain) < NWORK) {}  // <=31 blocks still running: brief
    }
    __syncthreads();
    __threadfence();
    float* TL = (float*)SM;  // reuse As/Bs space: 5376 floats = 21504 B
    for (int i = tid; i < NLAB * D_K; i += 256) TL[i] = aldf(T + i);
    if (tid < NLAB) Hl[tid] = aldi(hist + tid);
    __syncthreads();

    float wsum = 0.f;
    for (int it = 0; it < 64; ++it) {
      int row = slice * 256 + it * 4 + wv;
      int lab = labels[row];
      const uint* e4 = (const uint*)(e8 + (size_t)row * D_K);
      const float4* t4 = (const float4*)(TL + lab * D_K);
      float pd = 0.f, sd = 0.f;
#pragma unroll
      for (int j = 0; j < 3; ++j) {
        uint uu = e4[j * 64 + lane];
        float4 t = t4[j * 64 + lane];
        float a0 = dec8(uu & 0xff), a1 = dec8((uu >> 8) & 0xff);
        float a2 = dec8((uu >> 16) & 0xff), a3 = dec8(uu >> 24);
        pd += a0 * t.x + a1 * t.y + a2 * t.z + a3 * t.w;
        sd += a0 * a0 + a1 * a1 + a2 * a2 + a3 * a3;
      }
#pragma unroll
      for (int m = 1; m < 64; m <<= 1) {
        pd += __shfl_xor(pd, m);
        sd += __shfl_xor(sd, m);
      }
      if (lane == 0) {
        int ni = Hl[lab] - 1;
        float per = 0.f;
        if (ni > 0) per = MBOUND + __logf(aldf(rse + row)) - (pd - sd) / (float)ni;
        wsum += 0.9f * per + (0.1f / (float)B_N) * celoss[row];
      }
    }
    if (lane == 0) sPart[wv] = wsum;
    __syncthreads();
    if (tid == 0) {
      float bs = sPart[0] + sPart[1] + sPart[2] + sPart[3];
      atomicAdd(contr, bs);
      __threadfence();
      int n2 = atomicAdd(done2, 1);
      if (n2 == NTAIL - 1) {
        __threadfence();
        outv[0] = aldf(contr);
      }
    }
  }
}

extern "C" void kernel_launch(void* const* d_in, const int* in_sizes, int n_in,
                              void* d_out, int out_size, void* d_ws, size_t ws_size,
                              hipStream_t stream) {
  const float* cls    = (const float*)d_in[0];
  const float* pooled = (const float*)d_in[1];
  const int*   labels = (const int*)d_in[2];
  const float* W      = (const float*)d_in[3];
  const float* bias   = (const float*)d_in[4];
  float* outv = (float*)d_out;

  // workspace: e8 6291456 + tail 1463552 = 7,755,008 B (< 14,057,472 proven r8)
  char* ws = (char*)d_ws;
  unsigned char* e8 = (unsigned char*)ws;          // 6291456 B
  size_t off = (size_t)B_N * D_K;
  float* rse      = (float*)(ws + off);            // +0      (32768) [zeroed n1]
  int*   hist     = (int*)(ws + off + 32768);      // +32768  (28)    [zeroed n1]
  int*   doneA    = (int*)(ws + off + 32800);      // +32800  (4)     [zeroed n1]
  int*   doneMain = (int*)(ws + off + 32832);      // +32832  (4)     [zeroed n1]
  int*   done2    = (int*)(ws + off + 32864);      // +32864  (4)     [zeroed n1]
  float* contr    = (float*)(ws + off + 32896);    // +32896  (4)     [zeroed n1]
  float* T        = (float*)(ws + off + 33024);    // +33024  (21504, written n2-B)
  float* celoss   = (float*)(ws + off + 54528);    // +54528  (32768, written n1)
  float* partial  = (float*)(ws + off + 87296);    // +87296  (1376256, written n2-A)
  int*   zr       = (int*)(ws + off);              // 8256 ints: rse..contr

  k_prep<<<B_N / 4, 256, 0, stream>>>(cls, pooled, labels, W, bias, e8, outv + 1,
                                      celoss, zr);
  k_mega<<<GOFF + NTILE, 256, 0, stream>>>(e8, labels, rse, hist, doneA, doneMain,
                                           done2, contr, T, celoss, partial, outv);
}